// Round 9
// baseline (272.867 us; speedup 1.0000x reference)
//
#include <hip/hip_runtime.h>

#define DT 0.02f

typedef __attribute__((ext_vector_type(8))) __bf16 bf16x8;
typedef __attribute__((ext_vector_type(4))) __bf16 bf16x4;
typedef __attribute__((ext_vector_type(4))) float  f32x4;

__device__ __forceinline__ float fast_tanh(float x){
    // tanh(x) = 1 - 2/(exp(2x)+1); exp(2x) = exp2(x * 2*log2(e))
    float e = __builtin_amdgcn_exp2f(x * 2.8853900817779268f);
    return 1.0f - 2.0f * __builtin_amdgcn_rcpf(e + 1.0f);
}
// swizzled LDS address for X[m][j] bf16 tiles (64 rows x 128 cols), byte = m*256 + j*2
__device__ __forceinline__ char* ldsx(char* base, int m, int j){
    return base + (((m << 8) + (j << 1)) ^ ((m & 7) << 4));
}

// 128(hidden) x 64(sample) x 128(k) GEMM, FOUR waves: wave w owns hidden rows
// [32w, 32w+32) x all 64 samples.  D[r][c] = sum_k Wg[r][k]*X[c][k].
// A (weights) from global (L1/L2-hot), B (activations) from swizzled LDS tile [c][k].
// MODE 1: Obuf[c][r] = tanh(D + bias[r])            (write-only)
// MODE 0: Obuf[c][r] = D * (1 - Obuf[c][r]^2)       (in-place (1-h^2) mask RMW)
// MODE 3: Obuf[c][r] = D * Obuf[c][r]               (in-place precomputed-mask RMW;
//                                                    keeps epilogue register-lean so
//                                                    5 blocks/CU fits without spill)
template<int MODE>
__device__ __forceinline__ void hnn_gemm(const __bf16* __restrict__ Wg,
                                         char* Xbuf, char* Obuf,
                                         const float* __restrict__ bias,
                                         int w, int l)
{
    const int lr = l & 15, lg = l >> 4;
    const int rbase = w * 32;

    f32x4 acc[2][4];
    #pragma unroll
    for (int mt = 0; mt < 2; ++mt)
        #pragma unroll
        for (int nt = 0; nt < 4; ++nt) acc[mt][nt] = 0.0f;

    #pragma unroll
    for (int ks = 0; ks < 4; ++ks){
        const int kb = ks * 32 + lg * 8;
        bf16x8 a[2], b[4];
        #pragma unroll
        for (int mt = 0; mt < 2; ++mt)
            a[mt] = *(const bf16x8*)(Wg + ((rbase + mt * 16 + lr) << 7) + kb);
        #pragma unroll
        for (int nt = 0; nt < 4; ++nt)
            b[nt] = *(const bf16x8*)ldsx(Xbuf, nt * 16 + lr, kb);
        #pragma unroll
        for (int mt = 0; mt < 2; ++mt)
            #pragma unroll
            for (int nt = 0; nt < 4; ++nt)
                acc[mt][nt] = __builtin_amdgcn_mfma_f32_16x16x32_bf16(
                    a[mt], b[nt], acc[mt][nt], 0, 0, 0);
    }

    if (MODE == 1){
        #pragma unroll
        for (int mt = 0; mt < 2; ++mt){
            const int j0 = rbase + mt * 16 + lg * 4;
            const f32x4 bv = *(const f32x4*)(bias + j0);
            #pragma unroll
            for (int nt = 0; nt < 4; ++nt){
                const int m = nt * 16 + lr;
                bf16x4 hv;
                #pragma unroll
                for (int jr = 0; jr < 4; ++jr)
                    hv[jr] = (__bf16)fast_tanh(acc[mt][nt][jr] + bv[jr]);
                *(bf16x4*)ldsx(Obuf, m, j0) = hv;
            }
        }
    } else if (MODE == 0){
        #pragma unroll
        for (int mt = 0; mt < 2; ++mt){
            const int j0 = rbase + mt * 16 + lg * 4;
            #pragma unroll
            for (int nt = 0; nt < 4; ++nt){
                const int m = nt * 16 + lr;
                bf16x4* hp = (bf16x4*)ldsx(Obuf, m, j0);
                bf16x4 hv = *hp, gv;
                #pragma unroll
                for (int jr = 0; jr < 4; ++jr){
                    float h = (float)hv[jr];
                    gv[jr] = (__bf16)(acc[mt][nt][jr] * (1.0f - h * h));
                }
                *hp = gv;
            }
        }
    } else {                                   // MODE 3: multiply by stored mask
        #pragma unroll
        for (int mt = 0; mt < 2; ++mt){
            const int j0 = rbase + mt * 16 + lg * 4;
            #pragma unroll
            for (int nt = 0; nt < 4; ++nt){
                const int m = nt * 16 + lr;
                bf16x4* hp = (bf16x4*)ldsx(Obuf, m, j0);
                bf16x4 mv = *hp, gv;
                #pragma unroll
                for (int jr = 0; jr < 4; ++jr)
                    gv[jr] = (__bf16)(acc[mt][nt][jr] * (float)mv[jr]);
                *hp = gv;
            }
        }
    }
}

// prep: cast W2/W3 fp32 -> bf16 into ws (unswizzled):
// [0]=Wt2 ([n][k]), [16384]=Wt3, [32768]=W2 ([i][j]), [49152]=W3
__global__ void hnn_prep(const float* __restrict__ W2, const float* __restrict__ W3,
                         __bf16* __restrict__ ws)
{
    int idx = blockIdx.x * 256 + threadIdx.x;   // 0..16383
    int k = idx >> 7, n = idx & 127;
    __bf16 v2 = (__bf16)W2[idx];
    __bf16 v3 = (__bf16)W3[idx];
    ws[n * 128 + k]         = v2;
    ws[16384 + n * 128 + k] = v3;
    ws[32768 + idx]         = v2;
    ws[49152 + idx]         = v3;
}

__global__ __launch_bounds__(256, 5)
void hnn_main(const float* __restrict__ q, const float* __restrict__ p,
              const float* __restrict__ Fx,
              const float* __restrict__ W1, const float* __restrict__ b1,
              const float* __restrict__ b2, const float* __restrict__ b3,
              const float* __restrict__ W4,
              const __bf16* __restrict__ ws,
              float* __restrict__ out)
{
    __shared__ char bufA[16384];      // [64][128] bf16, swizzled
    __shared__ char bufB[16384];
    const int t = threadIdx.x;
    const int w = t >> 6, l = t & 63;
    const int lr = l & 15, lg = l >> 4;
    const long mg0 = (long)blockIdx.x * 64;

    // ---- phase 0: h1[m][j] = tanh(q*W1[0][j] + p*W1[1][j] + b1[j]) -> bufA
    // thread covers samples m = w*16 + i*4 + lg (i<4), j-block j0 = lr*8
    {
        const int j0 = lr * 8;
        f32x4 wq0 = *(const f32x4*)(W1 + j0),       wq1 = *(const f32x4*)(W1 + j0 + 4);
        f32x4 wp0 = *(const f32x4*)(W1 + 128 + j0), wp1 = *(const f32x4*)(W1 + 128 + j0 + 4);
        f32x4 bb0 = *(const f32x4*)(b1 + j0),       bb1 = *(const f32x4*)(b1 + j0 + 4);
        #pragma unroll
        for (int i = 0; i < 4; ++i){
            int m = w * 16 + i * 4 + lg;
            float qq = q[mg0 + m], pp = p[mg0 + m];
            bf16x8 hv;
            #pragma unroll
            for (int u = 0; u < 4; ++u){
                hv[u]     = (__bf16)fast_tanh(fmaf(qq, wq0[u], fmaf(pp, wp0[u], bb0[u])));
                hv[4 + u] = (__bf16)fast_tanh(fmaf(qq, wq1[u], fmaf(pp, wp1[u], bb1[u])));
            }
            *(bf16x8*)ldsx(bufA, m, j0) = hv;
        }
    }
    __syncthreads();
    hnn_gemm<1>(ws,         bufA, bufB, b2, w, l);   // h2 = tanh(h1@W2+b2) -> B
    __syncthreads();
    hnn_gemm<1>(ws + 16384, bufB, bufA, b3, w, l);   // h3 = tanh(h2@W3+b3) -> A
    __syncthreads();

    // ---- phase 3: g3[m][j] = W4[j] * (1 - h3[m][j]^2), in place in bufA
    {
        const int j0 = lr * 8;
        f32x4 w40 = *(const f32x4*)(W4 + j0), w41 = *(const f32x4*)(W4 + j0 + 4);
        #pragma unroll
        for (int i = 0; i < 4; ++i){
            int m = w * 16 + i * 4 + lg;
            bf16x8* ptr = (bf16x8*)ldsx(bufA, m, j0);
            bf16x8 hv = *ptr, gv;
            #pragma unroll
            for (int u = 0; u < 4; ++u){
                float h0 = (float)hv[u],     h1v = (float)hv[4 + u];
                gv[u]     = (__bf16)(w40[u] * (1.0f - h0 * h0));
                gv[4 + u] = (__bf16)(w41[u] * (1.0f - h1v * h1v));
            }
            *ptr = gv;
        }
    }
    __syncthreads();
    // g2 = (g3 @ W3^T)*(1-h2^2): B-frags from bufA(g3), in-place mask RMW in bufB
    hnn_gemm<0>(ws + 49152, bufA, bufB, nullptr, w, l);
    __syncthreads();

    // ---- phase 4.5: mask1[m][j] = 1 - h1^2 (h1 recomputed) -> bufA (g3 dead)
    {
        const int j0 = lr * 8;
        f32x4 wq0 = *(const f32x4*)(W1 + j0),       wq1 = *(const f32x4*)(W1 + j0 + 4);
        f32x4 wp0 = *(const f32x4*)(W1 + 128 + j0), wp1 = *(const f32x4*)(W1 + 128 + j0 + 4);
        f32x4 bb0 = *(const f32x4*)(b1 + j0),       bb1 = *(const f32x4*)(b1 + j0 + 4);
        #pragma unroll
        for (int i = 0; i < 4; ++i){
            int m = w * 16 + i * 4 + lg;
            float qq = q[mg0 + m], pp = p[mg0 + m];
            bf16x8 mv;
            #pragma unroll
            for (int u = 0; u < 4; ++u){
                float h0 = fast_tanh(fmaf(qq, wq0[u], fmaf(pp, wp0[u], bb0[u])));
                float h1v = fast_tanh(fmaf(qq, wq1[u], fmaf(pp, wp1[u], bb1[u])));
                mv[u]     = (__bf16)(1.0f - h0 * h0);
                mv[4 + u] = (__bf16)(1.0f - h1v * h1v);
            }
            *(bf16x8*)ldsx(bufA, m, j0) = mv;
        }
    }
    __syncthreads();
    // g1 = (g2 @ W2^T) * mask1: B-frags from bufB(g2), in-place mask RMW in bufA
    hnn_gemm<3>(ws + 32768, bufB, bufA, nullptr, w, l);
    __syncthreads();

    // ---- phase 6: dHdq[m] = sum_j g1[m][j]*W1[0][j], dHdp likewise
    // thread t: sample m = t&63, j-quarter q4 = t>>6 (32 j's each)
    {
        const int m = t & 63, q4 = t >> 6;
        float sdq = 0.f, sdp = 0.f;
        #pragma unroll
        for (int i = 0; i < 4; ++i){
            int j0 = q4 * 32 + i * 8;
            bf16x8 gv = *(const bf16x8*)ldsx(bufA, m, j0);
            f32x4 wq0 = *(const f32x4*)(W1 + j0),       wq1 = *(const f32x4*)(W1 + j0 + 4);
            f32x4 wp0 = *(const f32x4*)(W1 + 128 + j0), wp1 = *(const f32x4*)(W1 + 128 + j0 + 4);
            #pragma unroll
            for (int u = 0; u < 4; ++u){
                float g0 = (float)gv[u], g1v = (float)gv[4 + u];
                sdq = fmaf(g0, wq0[u], fmaf(g1v, wq1[u], sdq));
                sdp = fmaf(g0, wp0[u], fmaf(g1v, wp1[u], sdp));
            }
        }
        float2* red = (float2*)bufB;                // bufB dead; reuse as reduction buffer
        red[m * 4 + q4] = make_float2(sdq, sdp);
    }
    __syncthreads();
    if (t < 64){
        const float2* red = (const float2*)bufB;
        float2 r0 = red[t * 4 + 0], r1 = red[t * 4 + 1];
        float2 r2 = red[t * 4 + 2], r3 = red[t * 4 + 3];
        float dq = r0.x + r1.x + r2.x + r3.x;
        float dp = r0.y + r1.y + r2.y + r3.y;
        long gm = mg0 + t;
        float2 o;
        o.x = DT * dp;                      // dq_dt = dH/dp
        o.y = DT * (-dq + Fx[gm]);          // dp_dt = -dH/dq + F_ext
        *(float2*)(out + gm * 2) = o;
    }
}

extern "C" void kernel_launch(void* const* d_in, const int* in_sizes, int n_in,
                              void* d_out, int out_size, void* d_ws, size_t ws_size,
                              hipStream_t stream) {
    const float* q   = (const float*)d_in[0];
    const float* p   = (const float*)d_in[1];
    const float* Fx  = (const float*)d_in[2];
    const float* W1  = (const float*)d_in[3];
    const float* b1  = (const float*)d_in[4];
    const float* W2  = (const float*)d_in[5];
    const float* b2  = (const float*)d_in[6];
    const float* W3  = (const float*)d_in[7];
    const float* b3  = (const float*)d_in[8];
    const float* W4  = (const float*)d_in[9];
    // d_in[10] = b4 (unused: gradients do not depend on it)
    __bf16* ws = (__bf16*)d_ws;
    float* out = (float*)d_out;

    (void)in_sizes; (void)n_in; (void)out_size; (void)ws_size;

    hnn_prep<<<64, 256, 0, stream>>>(W2, W3, ws);
    hnn_main<<<8192, 256, 0, stream>>>(q, p, Fx, W1, b1, b2, b3, W4, ws, out);
}

// Round 10
// 234.064 us; speedup vs baseline: 1.1658x; 1.1658x over previous
//
#include <hip/hip_runtime.h>

#define DT 0.02f

typedef __attribute__((ext_vector_type(8))) __bf16 bf16x8;
typedef __attribute__((ext_vector_type(4))) __bf16 bf16x4;
typedef __attribute__((ext_vector_type(4))) float  f32x4;

__device__ __forceinline__ float fast_tanh(float x){
    // tanh(x) = 1 - 2/(exp(2x)+1); exp(2x) = exp2(x * 2*log2(e))
    float e = __builtin_amdgcn_exp2f(x * 2.8853900817779268f);
    return 1.0f - 2.0f * __builtin_amdgcn_rcpf(e + 1.0f);
}
// swizzled LDS address for X[m][j] bf16 tiles (64 rows x 128 cols), byte = m*256 + j*2
__device__ __forceinline__ char* ldsx(char* base, int m, int j){
    return base + (((m << 8) + (j << 1)) ^ ((m & 7) << 4));
}

// 128(hidden) x 64(sample) x 128(k) GEMM, FOUR waves: wave w owns hidden rows
// [32w, 32w+32) x all 64 samples.  D[r][c] = sum_k Wg[r][k]*X[c][k].
// A (weights) from global (L1/L2-hot), B (activations) from swizzled LDS tile [c][k].
// MODE 1: Obuf[c][r] = tanh(D + bias[r])                      (write-only)
// MODE 4: Obuf[c][r] = w4[r] * (1 - tanh(D + bias[r])^2)      (write-only, g3 direct)
// MODE 0: Obuf[c][r] = D * (1 - Obuf[c][r]^2)                 (in-place mask RMW)
// MODE 5: Obuf[c][r] = D * mask_reg[c][r]                     (write-only, reg mask)
template<int MODE>
__device__ __forceinline__ void hnn_gemm(const __bf16* __restrict__ Wg,
                                         char* Xbuf, char* Obuf,
                                         const float* __restrict__ bias,
                                         const float* __restrict__ w4,
                                         const bf16x4 (*m1)[4],
                                         int w, int l)
{
    const int lr = l & 15, lg = l >> 4;
    const int rbase = w * 32;

    f32x4 acc[2][4];
    #pragma unroll
    for (int mt = 0; mt < 2; ++mt)
        #pragma unroll
        for (int nt = 0; nt < 4; ++nt) acc[mt][nt] = 0.0f;

    #pragma unroll
    for (int ks = 0; ks < 4; ++ks){
        const int kb = ks * 32 + lg * 8;
        bf16x8 a[2], b[4];
        #pragma unroll
        for (int mt = 0; mt < 2; ++mt)
            a[mt] = *(const bf16x8*)(Wg + ((rbase + mt * 16 + lr) << 7) + kb);
        #pragma unroll
        for (int nt = 0; nt < 4; ++nt)
            b[nt] = *(const bf16x8*)ldsx(Xbuf, nt * 16 + lr, kb);
        #pragma unroll
        for (int mt = 0; mt < 2; ++mt)
            #pragma unroll
            for (int nt = 0; nt < 4; ++nt)
                acc[mt][nt] = __builtin_amdgcn_mfma_f32_16x16x32_bf16(
                    a[mt], b[nt], acc[mt][nt], 0, 0, 0);
    }

    if (MODE == 1){
        #pragma unroll
        for (int mt = 0; mt < 2; ++mt){
            const int j0 = rbase + mt * 16 + lg * 4;
            const f32x4 bv = *(const f32x4*)(bias + j0);
            #pragma unroll
            for (int nt = 0; nt < 4; ++nt){
                const int m = nt * 16 + lr;
                bf16x4 hv;
                #pragma unroll
                for (int jr = 0; jr < 4; ++jr)
                    hv[jr] = (__bf16)fast_tanh(acc[mt][nt][jr] + bv[jr]);
                *(bf16x4*)ldsx(Obuf, m, j0) = hv;
            }
        }
    } else if (MODE == 4){
        #pragma unroll
        for (int mt = 0; mt < 2; ++mt){
            const int j0 = rbase + mt * 16 + lg * 4;
            const f32x4 bv = *(const f32x4*)(bias + j0);
            const f32x4 wv = *(const f32x4*)(w4 + j0);
            #pragma unroll
            for (int nt = 0; nt < 4; ++nt){
                const int m = nt * 16 + lr;
                bf16x4 gv;
                #pragma unroll
                for (int jr = 0; jr < 4; ++jr){
                    float tt = fast_tanh(acc[mt][nt][jr] + bv[jr]);
                    gv[jr] = (__bf16)(wv[jr] * (1.0f - tt * tt));
                }
                *(bf16x4*)ldsx(Obuf, m, j0) = gv;
            }
        }
    } else if (MODE == 0){
        #pragma unroll
        for (int mt = 0; mt < 2; ++mt){
            const int j0 = rbase + mt * 16 + lg * 4;
            #pragma unroll
            for (int nt = 0; nt < 4; ++nt){
                const int m = nt * 16 + lr;
                bf16x4* hp = (bf16x4*)ldsx(Obuf, m, j0);
                bf16x4 hv = *hp, gv;
                #pragma unroll
                for (int jr = 0; jr < 4; ++jr){
                    float h = (float)hv[jr];
                    gv[jr] = (__bf16)(acc[mt][nt][jr] * (1.0f - h * h));
                }
                *hp = gv;
            }
        }
    } else {                                   // MODE 5: multiply by register mask
        #pragma unroll
        for (int mt = 0; mt < 2; ++mt){
            const int j0 = rbase + mt * 16 + lg * 4;
            #pragma unroll
            for (int nt = 0; nt < 4; ++nt){
                const int m = nt * 16 + lr;
                const bf16x4 mv = m1[mt][nt];
                bf16x4 gv;
                #pragma unroll
                for (int jr = 0; jr < 4; ++jr)
                    gv[jr] = (__bf16)(acc[mt][nt][jr] * (float)mv[jr]);
                *(bf16x4*)ldsx(Obuf, m, j0) = gv;
            }
        }
    }
}

// prep: cast W2/W3 fp32 -> bf16 into ws (unswizzled):
// [0]=Wt2 ([n][k]), [16384]=Wt3, [32768]=W2 ([i][j]), [49152]=W3
__global__ void hnn_prep(const float* __restrict__ W2, const float* __restrict__ W3,
                         __bf16* __restrict__ ws)
{
    int idx = blockIdx.x * 256 + threadIdx.x;   // 0..16383
    int k = idx >> 7, n = idx & 127;
    __bf16 v2 = (__bf16)W2[idx];
    __bf16 v3 = (__bf16)W3[idx];
    ws[n * 128 + k]         = v2;
    ws[16384 + n * 128 + k] = v3;
    ws[32768 + idx]         = v2;
    ws[49152 + idx]         = v3;
}

__global__ __launch_bounds__(256, 4)
void hnn_main(const float* __restrict__ q, const float* __restrict__ p,
              const float* __restrict__ Fx,
              const float* __restrict__ W1, const float* __restrict__ b1,
              const float* __restrict__ b2, const float* __restrict__ b3,
              const float* __restrict__ W4,
              const __bf16* __restrict__ ws,
              float* __restrict__ out)
{
    __shared__ char bufA[16384];      // [64][128] bf16, swizzled
    __shared__ char bufB[16384];
    const int t = threadIdx.x;
    const int w = t >> 6, l = t & 63;
    const int lr = l & 15, lg = l >> 4;
    const long mg0 = (long)blockIdx.x * 64;

    // ---- phase 0 (epilogue-layout): h1 = tanh(q*W1[0]+p*W1[1]+b1) -> bufA,
    //      and keep mask1 = 1-h1^2 in registers for G4's MODE-5 epilogue.
    //      thread covers (m = nt*16+lr, j = w*32 + mt*16 + lg*4 + jr)
    bf16x4 mask1[2][4];
    {
        const int rbase = w * 32;
        float qq[4], pp[4];
        #pragma unroll
        for (int nt = 0; nt < 4; ++nt){
            qq[nt] = q[mg0 + nt * 16 + lr];
            pp[nt] = p[mg0 + nt * 16 + lr];
        }
        #pragma unroll
        for (int mt = 0; mt < 2; ++mt){
            const int j0 = rbase + mt * 16 + lg * 4;
            const f32x4 wq = *(const f32x4*)(W1 + j0);
            const f32x4 wp = *(const f32x4*)(W1 + 128 + j0);
            const f32x4 bb = *(const f32x4*)(b1 + j0);
            #pragma unroll
            for (int nt = 0; nt < 4; ++nt){
                bf16x4 hv, mv;
                #pragma unroll
                for (int jr = 0; jr < 4; ++jr){
                    float h = fast_tanh(fmaf(qq[nt], wq[jr], fmaf(pp[nt], wp[jr], bb[jr])));
                    hv[jr] = (__bf16)h;
                    mv[jr] = (__bf16)(1.0f - h * h);
                }
                *(bf16x4*)ldsx(bufA, nt * 16 + lr, j0) = hv;
                mask1[mt][nt] = mv;
            }
        }
    }
    __syncthreads();
    // G1: h2 = tanh(h1@W2 + b2) -> bufB
    hnn_gemm<1>(ws,         bufA, bufB, b2, nullptr, nullptr, w, l);
    __syncthreads();
    // G2: g3 = W4 * (1 - tanh(h2@W3 + b3)^2) -> bufA   (phase-3 fused)
    hnn_gemm<4>(ws + 16384, bufB, bufA, b3, W4, nullptr, w, l);
    __syncthreads();
    // G3: g2 = (g3 @ W3^T) * (1 - h2^2): B-frags from bufA, RMW mask in bufB
    hnn_gemm<0>(ws + 49152, bufA, bufB, nullptr, nullptr, nullptr, w, l);
    __syncthreads();
    // G4: g1 = (g2 @ W2^T) * mask1_reg -> bufA
    hnn_gemm<5>(ws + 32768, bufB, bufA, nullptr, nullptr, mask1, w, l);
    __syncthreads();

    // ---- phase 6: dHdq[m] = sum_j g1[m][j]*W1[0][j], dHdp likewise
    // thread t: sample m = t&63, j-quarter q4 = t>>6 (32 j's each)
    {
        const int m = t & 63, q4 = t >> 6;
        float sdq = 0.f, sdp = 0.f;
        #pragma unroll
        for (int i = 0; i < 4; ++i){
            int j0 = q4 * 32 + i * 8;
            bf16x8 gv = *(const bf16x8*)ldsx(bufA, m, j0);
            f32x4 wq0 = *(const f32x4*)(W1 + j0),       wq1 = *(const f32x4*)(W1 + j0 + 4);
            f32x4 wp0 = *(const f32x4*)(W1 + 128 + j0), wp1 = *(const f32x4*)(W1 + 128 + j0 + 4);
            #pragma unroll
            for (int u = 0; u < 4; ++u){
                float g0 = (float)gv[u], g1v = (float)gv[4 + u];
                sdq = fmaf(g0, wq0[u], fmaf(g1v, wq1[u], sdq));
                sdp = fmaf(g0, wp0[u], fmaf(g1v, wp1[u], sdp));
            }
        }
        float2* red = (float2*)bufB;                // bufB dead; reuse as reduction buffer
        red[m * 4 + q4] = make_float2(sdq, sdp);
    }
    __syncthreads();
    if (t < 64){
        const float2* red = (const float2*)bufB;
        float2 r0 = red[t * 4 + 0], r1 = red[t * 4 + 1];
        float2 r2 = red[t * 4 + 2], r3 = red[t * 4 + 3];
        float dq = r0.x + r1.x + r2.x + r3.x;
        float dp = r0.y + r1.y + r2.y + r3.y;
        long gm = mg0 + t;
        float2 o;
        o.x = DT * dp;                      // dq_dt = dH/dp
        o.y = DT * (-dq + Fx[gm]);          // dp_dt = -dH/dq + F_ext
        *(float2*)(out + gm * 2) = o;
    }
}

extern "C" void kernel_launch(void* const* d_in, const int* in_sizes, int n_in,
                              void* d_out, int out_size, void* d_ws, size_t ws_size,
                              hipStream_t stream) {
    const float* q   = (const float*)d_in[0];
    const float* p   = (const float*)d_in[1];
    const float* Fx  = (const float*)d_in[2];
    const float* W1  = (const float*)d_in[3];
    const float* b1  = (const float*)d_in[4];
    const float* W2  = (const float*)d_in[5];
    const float* b2  = (const float*)d_in[6];
    const float* W3  = (const float*)d_in[7];
    const float* b3  = (const float*)d_in[8];
    const float* W4  = (const float*)d_in[9];
    // d_in[10] = b4 (unused: gradients do not depend on it)
    __bf16* ws = (__bf16*)d_ws;
    float* out = (float*)d_out;

    (void)in_sizes; (void)n_in; (void)out_size; (void)ws_size;

    hnn_prep<<<64, 256, 0, stream>>>(W2, W3, ws);
    hnn_main<<<8192, 256, 0, stream>>>(q, p, Fx, W1, b1, b2, b3, W4, ws, out);
}

// Round 14
// 198.955 us; speedup vs baseline: 1.3715x; 1.1765x over previous
//
#include <hip/hip_runtime.h>

#define DT 0.02f

typedef __attribute__((ext_vector_type(8))) __bf16 bf16x8;
typedef __attribute__((ext_vector_type(4))) __bf16 bf16x4;
typedef __attribute__((ext_vector_type(4))) float  f32x4;

__device__ __forceinline__ float fast_tanh(float x){
    float e = __builtin_amdgcn_exp2f(x * 2.8853900817779268f);
    return 1.0f - 2.0f * __builtin_amdgcn_rcpf(e + 1.0f);
}
// swizzled LDS address for X[m][j] bf16 tiles (128 rows x 128 cols), byte = m*256 + j*2
__device__ __forceinline__ char* ldsx(char* base, int m, int j){
    return base + (((m << 8) + (j << 1)) ^ ((m & 7) << 4));
}

// load A-frags (weights, global L1/L2-hot) for one GEMM: wave w owns rows [16w,16w+16)
__device__ __forceinline__ void ld_afrag(const __bf16* __restrict__ Wg, int w, int l,
                                         bf16x8 a[4]){
    const int lr = l & 15, lg = l >> 4;
    const __bf16* row = Wg + ((w * 16 + lr) << 7) + lg * 8;
    #pragma unroll
    for (int ks = 0; ks < 4; ++ks) a[ks] = *(const bf16x8*)(row + ks * 32);
}

// 128(hidden rows, 16/wave) x 128(sample) x 128(k) GEMM, EIGHT waves.
// D[r][c] = sum_k Wg[r][k]*X[c][k]; A-frags preloaded (a[4], barrier-independent),
// B (activations) from swizzled LDS [c][k]. If PRE, prefetch next GEMM's A-frags
// between MFMA loop and epilogue (hides global latency under epilogue+barrier).
// MODE 1: Obuf[c][r] = tanh(D + bias[r])                 (write-only)
// MODE 4: Obuf[c][r] = w4[r]*(1 - tanh(D + bias[r])^2)   (write-only, g3 direct)
// MODE 0: Obuf[c][r] = D * (1 - Obuf[c][r]^2)            (in-place mask RMW)
// MODE 5: Obuf[c][r] = D * m1[c][r]                      (write-only, register mask)
template<int MODE, bool PRE>
__device__ __forceinline__ void hnn_gemm(const bf16x8 a[4],
                                         const __bf16* __restrict__ Wnext, bf16x8 anext[4],
                                         char* Xbuf, char* Obuf,
                                         const float* __restrict__ bias,
                                         const float* __restrict__ w4,
                                         const bf16x4* m1,
                                         int w, int l)
{
    const int lr = l & 15, lg = l >> 4;
    const int j0 = w * 16 + lg * 4;

    f32x4 acc[8];
    #pragma unroll
    for (int nt = 0; nt < 8; ++nt) acc[nt] = 0.0f;

    #pragma unroll
    for (int ks = 0; ks < 4; ++ks){
        const int kb = ks * 32 + lg * 8;
        bf16x8 b[8];
        #pragma unroll
        for (int nt = 0; nt < 8; ++nt)
            b[nt] = *(const bf16x8*)ldsx(Xbuf, nt * 16 + lr, kb);
        #pragma unroll
        for (int nt = 0; nt < 8; ++nt)
            acc[nt] = __builtin_amdgcn_mfma_f32_16x16x32_bf16(a[ks], b[nt], acc[nt], 0, 0, 0);
    }

    if (PRE) ld_afrag(Wnext, w, l, anext);   // issue early; latency hides under epilogue

    if (MODE == 1){
        const f32x4 bv = *(const f32x4*)(bias + j0);
        #pragma unroll
        for (int nt = 0; nt < 8; ++nt){
            bf16x4 hv;
            #pragma unroll
            for (int jr = 0; jr < 4; ++jr)
                hv[jr] = (__bf16)fast_tanh(acc[nt][jr] + bv[jr]);
            *(bf16x4*)ldsx(Obuf, nt * 16 + lr, j0) = hv;
        }
    } else if (MODE == 4){
        const f32x4 bv = *(const f32x4*)(bias + j0);
        const f32x4 wv = *(const f32x4*)(w4 + j0);
        #pragma unroll
        for (int nt = 0; nt < 8; ++nt){
            bf16x4 gv;
            #pragma unroll
            for (int jr = 0; jr < 4; ++jr){
                float tt = fast_tanh(acc[nt][jr] + bv[jr]);
                gv[jr] = (__bf16)(wv[jr] * (1.0f - tt * tt));
            }
            *(bf16x4*)ldsx(Obuf, nt * 16 + lr, j0) = gv;
        }
    } else if (MODE == 0){
        #pragma unroll
        for (int nt = 0; nt < 8; ++nt){
            bf16x4* hp = (bf16x4*)ldsx(Obuf, nt * 16 + lr, j0);
            bf16x4 hv = *hp, gv;
            #pragma unroll
            for (int jr = 0; jr < 4; ++jr){
                float h = (float)hv[jr];
                gv[jr] = (__bf16)(acc[nt][jr] * (1.0f - h * h));
            }
            *hp = gv;
        }
    } else {                                  // MODE 5
        #pragma unroll
        for (int nt = 0; nt < 8; ++nt){
            const bf16x4 mv = m1[nt];
            bf16x4 gv;
            #pragma unroll
            for (int jr = 0; jr < 4; ++jr)
                gv[jr] = (__bf16)(acc[nt][jr] * (float)mv[jr]);
            *(bf16x4*)ldsx(Obuf, nt * 16 + lr, j0) = gv;
        }
    }
}

// prep: cast W2/W3 fp32 -> bf16 into ws (unswizzled):
// [0]=Wt2 ([n][k]), [16384]=Wt3, [32768]=W2 ([i][j]), [49152]=W3
__global__ void hnn_prep(const float* __restrict__ W2, const float* __restrict__ W3,
                         __bf16* __restrict__ ws)
{
    int idx = blockIdx.x * 256 + threadIdx.x;   // 0..16383
    int k = idx >> 7, n = idx & 127;
    __bf16 v2 = (__bf16)W2[idx];
    __bf16 v3 = (__bf16)W3[idx];
    ws[n * 128 + k]         = v2;
    ws[16384 + n * 128 + k] = v3;
    ws[32768 + idx]         = v2;
    ws[49152 + idx]         = v3;
}

__global__ __launch_bounds__(512, 4)
void hnn_main(const float* __restrict__ q, const float* __restrict__ p,
              const float* __restrict__ Fx,
              const float* __restrict__ W1, const float* __restrict__ b1,
              const float* __restrict__ b2, const float* __restrict__ b3,
              const float* __restrict__ W4,
              const __bf16* __restrict__ ws,
              float* __restrict__ out)
{
    __shared__ char bufA[32768];      // [128][128] bf16, swizzled
    __shared__ char bufB[32768];
    const int t = threadIdx.x;
    const int w = t >> 6, l = t & 63;
    const int lr = l & 15, lg = l >> 4;
    const long mg0 = (long)blockIdx.x * 128;

    // ---- phase 0 (epilogue-layout): h1 = tanh(q*W1[0]+p*W1[1]+b1) -> bufA,
    //      keep mask1 = 1-h1^2 in registers for G4's MODE-5 epilogue.
    //      thread covers (m = nt*16+lr, j = w*16 + lg*4 + jr)
    bf16x4 mask1[8];
    bf16x8 aF[4], aG[4];
    {
        const int j0 = w * 16 + lg * 4;
        const f32x4 wq = *(const f32x4*)(W1 + j0);
        const f32x4 wp = *(const f32x4*)(W1 + 128 + j0);
        const f32x4 bb = *(const f32x4*)(b1 + j0);
        #pragma unroll
        for (int nt = 0; nt < 8; ++nt){
            const int m = nt * 16 + lr;
            float qq = q[mg0 + m], pp = p[mg0 + m];
            bf16x4 hv, mv;
            #pragma unroll
            for (int jr = 0; jr < 4; ++jr){
                float h = fast_tanh(fmaf(qq, wq[jr], fmaf(pp, wp[jr], bb[jr])));
                hv[jr] = (__bf16)h;
                mv[jr] = (__bf16)(1.0f - h * h);
            }
            *(bf16x4*)ldsx(bufA, m, j0) = hv;
            mask1[nt] = mv;
        }
    }
    ld_afrag(ws, w, l, aF);                      // A for G1 (Wt2), before barrier
    __syncthreads();
    // G1: h2 = tanh(h1@W2 + b2) -> bufB; prefetch Wt3
    hnn_gemm<1, true >(aF, ws + 16384, aG, bufA, bufB, b2, nullptr, nullptr, w, l);
    __syncthreads();
    // G2: g3 = W4*(1 - tanh(h2@W3 + b3)^2) -> bufA; prefetch W3
    hnn_gemm<4, true >(aG, ws + 49152, aF, bufB, bufA, b3, W4, nullptr, w, l);
    __syncthreads();
    // G3: g2 = (g3@W3^T)*(1-h2^2), RMW in bufB; prefetch W2
    hnn_gemm<0, true >(aF, ws + 32768, aG, bufA, bufB, nullptr, nullptr, nullptr, w, l);
    __syncthreads();
    // G4: g1 = (g2@W2^T) * mask1_reg -> bufA
    hnn_gemm<5, false>(aG, nullptr, aF, bufB, bufA, nullptr, nullptr, mask1, w, l);
    __syncthreads();

    // ---- phase 6: dHdq[m] = sum_j g1[m][j]*W1[0][j], dHdp likewise
    // thread t: sample m = t&127, j-quarter q4 = t>>7 (32 j's each)
    {
        const int m = t & 127, q4 = t >> 7;
        float sdq = 0.f, sdp = 0.f;
        #pragma unroll
        for (int i = 0; i < 4; ++i){
            int j0 = q4 * 32 + i * 8;
            bf16x8 gv = *(const bf16x8*)ldsx(bufA, m, j0);
            f32x4 wq0 = *(const f32x4*)(W1 + j0),       wq1 = *(const f32x4*)(W1 + j0 + 4);
            f32x4 wp0 = *(const f32x4*)(W1 + 128 + j0), wp1 = *(const f32x4*)(W1 + 128 + j0 + 4);
            #pragma unroll
            for (int u = 0; u < 4; ++u){
                float g0 = (float)gv[u], g1v = (float)gv[4 + u];
                sdq = fmaf(g0, wq0[u], fmaf(g1v, wq1[u], sdq));
                sdp = fmaf(g0, wp0[u], fmaf(g1v, wp1[u], sdp));
            }
        }
        float2* red = (float2*)bufB;                // bufB dead; reuse as reduction buffer
        red[m * 4 + q4] = make_float2(sdq, sdp);
    }
    __syncthreads();
    if (t < 128){
        const float2* red = (const float2*)bufB;
        float2 r0 = red[t * 4 + 0], r1 = red[t * 4 + 1];
        float2 r2 = red[t * 4 + 2], r3 = red[t * 4 + 3];
        float dq = r0.x + r1.x + r2.x + r3.x;
        float dp = r0.y + r1.y + r2.y + r3.y;
        long gm = mg0 + t;
        float2 o;
        o.x = DT * dp;                      // dq_dt = dH/dp
        o.y = DT * (-dq + Fx[gm]);          // dp_dt = -dH/dq + F_ext
        *(float2*)(out + gm * 2) = o;
    }
}

extern "C" void kernel_launch(void* const* d_in, const int* in_sizes, int n_in,
                              void* d_out, int out_size, void* d_ws, size_t ws_size,
                              hipStream_t stream) {
    const float* q   = (const float*)d_in[0];
    const float* p   = (const float*)d_in[1];
    const float* Fx  = (const float*)d_in[2];
    const float* W1  = (const float*)d_in[3];
    const float* b1  = (const float*)d_in[4];
    const float* W2  = (const float*)d_in[5];
    const float* b2  = (const float*)d_in[6];
    const float* W3  = (const float*)d_in[7];
    const float* b3  = (const float*)d_in[8];
    const float* W4  = (const float*)d_in[9];
    // d_in[10] = b4 (unused: gradients do not depend on it)
    __bf16* ws = (__bf16*)d_ws;
    float* out = (float*)d_out;

    (void)in_sizes; (void)n_in; (void)out_size; (void)ws_size;

    hnn_prep<<<64, 256, 0, stream>>>(W2, W3, ws);
    hnn_main<<<4096, 512, 0, stream>>>(q, p, Fx, W1, b1, b2, b3, W4, ws, out);
}